// Round 1
// baseline (216.195 us; speedup 1.0000x reference)
//
#include <hip/hip_runtime.h>

typedef unsigned short u16;
typedef unsigned int u32;

#define H_ 12
#define DH_ 64
#define D_ 768
#define S_ 1024
#define B_ 8
#define M_TOT 8192   // B_*S_

using f32x4  = __attribute__((ext_vector_type(4))) float;
using bf16x8 = __attribute__((ext_vector_type(8))) short;

__device__ inline u16 f2bf(float f) {
  union { float f; u32 u; } v; v.f = f;
  u32 r = v.u + 0x7FFFu + ((v.u >> 16) & 1u);
  return (u16)(r >> 16);
}

// ---------------- conversion: f32 -> bf16 for X and weights ----------------
__global__ void convert_all(const float* __restrict__ X,
                            const float* __restrict__ Wq, const float* __restrict__ Wk,
                            const float* __restrict__ Wv, const float* __restrict__ Wd,
                            u16* __restrict__ Xb, u16* __restrict__ Wqkv, u16* __restrict__ Wdb) {
  int stride = gridDim.x * blockDim.x;
  int tid = blockIdx.x * blockDim.x + threadIdx.x;
  const int NX = M_TOT * D_;
  const int NW = D_ * D_;
  for (int i = tid; i < NX; i += stride) Xb[i] = f2bf(X[i]);
  for (int i = tid; i < NW; i += stride) {
    Wqkv[i]        = f2bf(Wq[i]);
    Wqkv[NW + i]   = f2bf(Wk[i]);
    Wqkv[2*NW + i] = f2bf(Wv[i]);
    Wdb[i]         = f2bf(Wd[i]);
  }
}

// ---------------- GEMM 1: QKV projection ----------------
// C[m,n] = sum_k Xb[m,k] * Wqkv[n,k]  (B^T layout), epilogue: +bias, Q scaled 1/8,
// scatter into Q/K/V bf16 buffers laid out [B*S, D] (col = h*64+d).
#define BM 128
#define BN 128
#define BK 32
#define LDP 40   // padded LDS row stride (elements)

__global__ __launch_bounds__(256) void gemm_qkv(
    const u16* __restrict__ A, const u16* __restrict__ Bw,
    const float* __restrict__ bq, const float* __restrict__ bk, const float* __restrict__ bv,
    u16* __restrict__ Q, u16* __restrict__ K, u16* __restrict__ V) {
  __shared__ u16 As[BM * LDP];
  __shared__ u16 Bs[BN * LDP];
  int tid = threadIdx.x;
  int m0 = blockIdx.y * BM;
  int n0 = blockIdx.x * BN;     // 0..2176 over 2304
  int lane = tid & 63, wave = tid >> 6;
  int wm = (wave >> 1) * 64, wn = (wave & 1) * 64;
  int fr = lane & 15, fg = lane >> 4;
  f32x4 acc[4][4] = {};

  int srow = tid >> 1;
  int scol = (tid & 1) * 16;
  const u16* Ag = A  + (m0 + srow) * D_ + scol;
  const u16* Bg = Bw + (n0 + srow) * D_ + scol;
  u16* Asw = &As[srow * LDP + scol];
  u16* Bsw = &Bs[srow * LDP + scol];

  for (int k0 = 0; k0 < D_; k0 += BK) {
    int4 a0 = *(const int4*)(Ag + k0);
    int4 a1 = *(const int4*)(Ag + k0 + 8);
    int4 b0 = *(const int4*)(Bg + k0);
    int4 b1 = *(const int4*)(Bg + k0 + 8);
    __syncthreads();
    *(int4*)(Asw) = a0; *(int4*)(Asw + 8) = a1;
    *(int4*)(Bsw) = b0; *(int4*)(Bsw + 8) = b1;
    __syncthreads();
    bf16x8 af[4], bf[4];
#pragma unroll
    for (int i = 0; i < 4; i++) {
      af[i] = *(const bf16x8*)&As[(wm + i*16 + fr) * LDP + fg*8];
      bf[i] = *(const bf16x8*)&Bs[(wn + i*16 + fr) * LDP + fg*8];
    }
#pragma unroll
    for (int mi = 0; mi < 4; mi++)
#pragma unroll
      for (int ni = 0; ni < 4; ni++)
        acc[mi][ni] = __builtin_amdgcn_mfma_f32_16x16x32_bf16(af[mi], bf[ni], acc[mi][ni], 0, 0, 0);
  }

  int which = n0 / D_;
  int ncol0 = n0 % D_;
  const float* bias = (which == 0) ? bq : (which == 1) ? bk : bv;
  u16* Out = (which == 0) ? Q : (which == 1) ? K : V;
  float scale = (which == 0) ? 0.125f : 1.0f;
#pragma unroll
  for (int mi = 0; mi < 4; mi++)
#pragma unroll
    for (int ni = 0; ni < 4; ni++) {
      int col = ncol0 + wn + ni*16 + fr;
      float bb = bias[col];
#pragma unroll
      for (int r = 0; r < 4; r++) {
        int row = m0 + wm + mi*16 + fg*4 + r;
        Out[row * D_ + col] = f2bf((acc[mi][ni][r] + bb) * scale);
      }
    }
}

// ---------------- Attention (flash-style) ----------------
// grid (16, 96): x = q-tile of 64 rows, y = b*H+h. 4 waves, 16 q-rows each.
#define KB 64
#define LDK 72

__global__ __launch_bounds__(256) void attn_kernel(
    const u16* __restrict__ Q, const u16* __restrict__ K, const u16* __restrict__ V,
    const float* __restrict__ mask, u16* __restrict__ Ctx) {
  __shared__ u16 Ks[KB * LDK];
  __shared__ u16 Vt[DH_ * LDK];       // Vt[d][kcol]
  __shared__ u16 Ps[4 * 16 * LDK];    // per-wave P tile
  int tid = threadIdx.x, lane = tid & 63, wave = tid >> 6;
  int qt = blockIdx.x;
  int bh = blockIdx.y;
  int b = bh / H_, h = bh % H_;
  int q0 = qt * 64 + wave * 16;
  int fr = lane & 15, fg = lane >> 4;

  const u16* Qrow = Q + (b * S_ + q0 + fr) * D_ + h * DH_;
  bf16x8 qf[2];
  qf[0] = *(const bf16x8*)(Qrow + fg * 8);
  qf[1] = *(const bf16x8*)(Qrow + 32 + fg * 8);

  float m_run[4], l_run[4];
#pragma unroll
  for (int r = 0; r < 4; r++) { m_run[r] = -INFINITY; l_run[r] = 0.f; }
  f32x4 acc[4] = {};

  int srow = tid >> 2;            // 0..63
  int scc = (tid & 3) * 16;       // 0,16,32,48

  for (int kt = 0; kt < S_ / KB; kt++) {
    __syncthreads();
    {
      const u16* Kg = K + (b * S_ + kt * KB + srow) * D_ + h * DH_ + scc;
      *(int4*)&Ks[srow * LDK + scc]     = *(const int4*)Kg;
      *(int4*)&Ks[srow * LDK + scc + 8] = *(const int4*)(Kg + 8);
      const u16* Vg = V + (b * S_ + kt * KB + srow) * D_ + h * DH_ + scc;
      u16 tv[16];
      *(int4*)&tv[0] = *(const int4*)Vg;
      *(int4*)&tv[8] = *(const int4*)(Vg + 8);
#pragma unroll
      for (int j = 0; j < 16; j++) Vt[(scc + j) * LDK + srow] = tv[j];
    }
    __syncthreads();

    // S = Q K^T (pre-scaled by 1/8 via Q) + mask
    f32x4 sacc[4];
#pragma unroll
    for (int ns = 0; ns < 4; ns++) {
      bf16x8 kf0 = *(const bf16x8*)&Ks[(ns*16 + fr) * LDK + fg*8];
      bf16x8 kf1 = *(const bf16x8*)&Ks[(ns*16 + fr) * LDK + 32 + fg*8];
      f32x4 sv = {};
      sv = __builtin_amdgcn_mfma_f32_16x16x32_bf16(qf[0], kf0, sv, 0, 0, 0);
      sv = __builtin_amdgcn_mfma_f32_16x16x32_bf16(qf[1], kf1, sv, 0, 0, 0);
      float mv = mask[b * S_ + kt * KB + ns*16 + fr];
      sv[0] += mv; sv[1] += mv; sv[2] += mv; sv[3] += mv;
      sacc[ns] = sv;
    }

    // online softmax (rows = fg*4+r, cols spread over 16 lanes of group fg)
#pragma unroll
    for (int r = 0; r < 4; r++) {
      float mx = fmaxf(fmaxf(sacc[0][r], sacc[1][r]), fmaxf(sacc[2][r], sacc[3][r]));
#pragma unroll
      for (int m = 1; m < 16; m <<= 1) mx = fmaxf(mx, __shfl_xor(mx, m));
      float mnew = fmaxf(m_run[r], mx);
      float alpha = __expf(m_run[r] - mnew);
      float ps = 0.f;
#pragma unroll
      for (int ns = 0; ns < 4; ns++) {
        float p = __expf(sacc[ns][r] - mnew);
        sacc[ns][r] = p;
        ps += p;
      }
#pragma unroll
      for (int m = 1; m < 16; m <<= 1) ps += __shfl_xor(ps, m);
      l_run[r] = l_run[r] * alpha + ps;
      m_run[r] = mnew;
#pragma unroll
      for (int ns = 0; ns < 4; ns++) acc[ns][r] *= alpha;
    }

    // P -> LDS (per-wave region), then PV
    u16* Pw = &Ps[wave * 16 * LDK];
#pragma unroll
    for (int ns = 0; ns < 4; ns++)
#pragma unroll
      for (int r = 0; r < 4; r++)
        Pw[(fg*4 + r) * LDK + ns*16 + fr] = f2bf(sacc[ns][r]);

    bf16x8 pf0 = *(const bf16x8*)&Pw[fr * LDK + fg*8];
    bf16x8 pf1 = *(const bf16x8*)&Pw[fr * LDK + 32 + fg*8];
#pragma unroll
    for (int ns = 0; ns < 4; ns++) {
      bf16x8 vf0 = *(const bf16x8*)&Vt[(ns*16 + fr) * LDK + fg*8];
      bf16x8 vf1 = *(const bf16x8*)&Vt[(ns*16 + fr) * LDK + 32 + fg*8];
      acc[ns] = __builtin_amdgcn_mfma_f32_16x16x32_bf16(pf0, vf0, acc[ns], 0, 0, 0);
      acc[ns] = __builtin_amdgcn_mfma_f32_16x16x32_bf16(pf1, vf1, acc[ns], 0, 0, 0);
    }
  }

  u16* Crow = Ctx + (b * S_ + q0) * D_ + h * DH_;
#pragma unroll
  for (int ns = 0; ns < 4; ns++)
#pragma unroll
    for (int r = 0; r < 4; r++)
      Crow[(fg*4 + r) * D_ + ns*16 + fr] = f2bf(acc[ns][r] / l_run[r]);
}

// ---------------- GEMM 2: output projection + bias + residual ----------------
__global__ __launch_bounds__(256) void gemm_out(
    const u16* __restrict__ A, const u16* __restrict__ Bw,
    const float* __restrict__ bd, const float* __restrict__ hidden,
    float* __restrict__ Tmp) {
  __shared__ u16 As[BM * LDP];
  __shared__ u16 Bs[BN * LDP];
  int tid = threadIdx.x;
  int m0 = blockIdx.y * BM;
  int n0 = blockIdx.x * BN;     // 0..640
  int lane = tid & 63, wave = tid >> 6;
  int wm = (wave >> 1) * 64, wn = (wave & 1) * 64;
  int fr = lane & 15, fg = lane >> 4;
  f32x4 acc[4][4] = {};

  int srow = tid >> 1;
  int scol = (tid & 1) * 16;
  const u16* Ag = A  + (m0 + srow) * D_ + scol;
  const u16* Bg = Bw + (n0 + srow) * D_ + scol;
  u16* Asw = &As[srow * LDP + scol];
  u16* Bsw = &Bs[srow * LDP + scol];

  for (int k0 = 0; k0 < D_; k0 += BK) {
    int4 a0 = *(const int4*)(Ag + k0);
    int4 a1 = *(const int4*)(Ag + k0 + 8);
    int4 b0 = *(const int4*)(Bg + k0);
    int4 b1 = *(const int4*)(Bg + k0 + 8);
    __syncthreads();
    *(int4*)(Asw) = a0; *(int4*)(Asw + 8) = a1;
    *(int4*)(Bsw) = b0; *(int4*)(Bsw + 8) = b1;
    __syncthreads();
    bf16x8 af[4], bf[4];
#pragma unroll
    for (int i = 0; i < 4; i++) {
      af[i] = *(const bf16x8*)&As[(wm + i*16 + fr) * LDP + fg*8];
      bf[i] = *(const bf16x8*)&Bs[(wn + i*16 + fr) * LDP + fg*8];
    }
#pragma unroll
    for (int mi = 0; mi < 4; mi++)
#pragma unroll
      for (int ni = 0; ni < 4; ni++)
        acc[mi][ni] = __builtin_amdgcn_mfma_f32_16x16x32_bf16(af[mi], bf[ni], acc[mi][ni], 0, 0, 0);
  }

#pragma unroll
  for (int mi = 0; mi < 4; mi++)
#pragma unroll
    for (int ni = 0; ni < 4; ni++) {
      int col = n0 + wn + ni*16 + fr;
      float bb = bd[col];
#pragma unroll
      for (int r = 0; r < 4; r++) {
        int row = m0 + wm + mi*16 + fg*4 + r;
        Tmp[row * D_ + col] = acc[mi][ni][r] + bb + hidden[row * D_ + col];
      }
    }
}

// ---------------- LayerNorm ----------------
__global__ __launch_bounds__(256) void ln_kernel(
    const float* __restrict__ Tmp, const float* __restrict__ g,
    const float* __restrict__ bta, float* __restrict__ out) {
  int row = blockIdx.x;
  const float* x = Tmp + (size_t)row * D_;
  int tid = threadIdx.x;
  float v[3];
  float s = 0.f, s2 = 0.f;
#pragma unroll
  for (int i = 0; i < 3; i++) {
    v[i] = x[tid + i * 256];
    s += v[i]; s2 += v[i] * v[i];
  }
#pragma unroll
  for (int m = 1; m < 64; m <<= 1) { s += __shfl_xor(s, m); s2 += __shfl_xor(s2, m); }
  __shared__ float ws[8];
  int wave = tid >> 6, lane = tid & 63;
  if (lane == 0) { ws[wave] = s; ws[4 + wave] = s2; }
  __syncthreads();
  s  = ws[0] + ws[1] + ws[2] + ws[3];
  s2 = ws[4] + ws[5] + ws[6] + ws[7];
  float mean = s * (1.0f / D_);
  float var = s2 * (1.0f / D_) - mean * mean;
  float inv = rsqrtf(var + 1e-12f);
#pragma unroll
  for (int i = 0; i < 3; i++) {
    int c = tid + i * 256;
    out[(size_t)row * D_ + c] = (v[i] - mean) * inv * g[c] + bta[c];
  }
}

// ---------------- launch ----------------
extern "C" void kernel_launch(void* const* d_in, const int* in_sizes, int n_in,
                              void* d_out, int out_size, void* d_ws, size_t ws_size,
                              hipStream_t stream) {
  (void)in_sizes; (void)n_in; (void)out_size; (void)ws_size;
  const float* hidden = (const float*)d_in[0];
  const float* mask   = (const float*)d_in[1];
  const float* Wq = (const float*)d_in[2];
  const float* bq = (const float*)d_in[3];
  const float* Wk = (const float*)d_in[4];
  const float* bk = (const float*)d_in[5];
  const float* Wv = (const float*)d_in[6];
  const float* bv = (const float*)d_in[7];
  const float* Wd = (const float*)d_in[8];
  const float* bd = (const float*)d_in[9];
  const float* ln_g = (const float*)d_in[10];
  const float* ln_b = (const float*)d_in[11];
  float* out = (float*)d_out;

  char* ws = (char*)d_ws;
  u16* Xb    = (u16*)(ws);                 // 12,582,912 B
  u16* Wqkv  = (u16*)(ws + 12582912);      //  3,538,944 B
  u16* Wdb   = (u16*)(ws + 16121856);      //  1,179,648 B
  u16* Q     = (u16*)(ws + 17301504);      // 12,582,912 B
  u16* K     = (u16*)(ws + 29884416);      // 12,582,912 B
  u16* V     = (u16*)(ws + 42467328);      // 12,582,912 B
  u16* Ctx   = (u16*)(ws + 55050240);      // 12,582,912 B
  float* Tmp = (float*)(ws + 17301504);    // aliases dead Q+K, 25,165,824 B
  // high-water: 67,633,152 B

  convert_all<<<2048, 256, 0, stream>>>(hidden, Wq, Wk, Wv, Wd, Xb, Wqkv, Wdb);
  gemm_qkv<<<dim3(18, 64), 256, 0, stream>>>(Xb, Wqkv, bq, bk, bv, Q, K, V);
  attn_kernel<<<dim3(16, 96), 256, 0, stream>>>(Q, K, V, mask, Ctx);
  gemm_out<<<dim3(6, 64), 256, 0, stream>>>(Ctx, Wdb, bd, hidden, Tmp);
  ln_kernel<<<8192, 256, 0, stream>>>(Tmp, ln_g, ln_b, out);
}